// Round 10
// baseline (195.294 us; speedup 1.0000x reference)
//
#include <hip/hip_runtime.h>

// CrossAttention on MI355X (gfx950), bf16 MFMA path.
// B=4, Lq=2048, Lkv=512, dim_q=1024, dim_kv=768, H=8, hd=128.
// R21: R20's fp32-A inline-cast proj with COALESCED A loads. R20 counters:
//      proj 58us, MfmaUtil 15.8%, 1.2TB/s -- A loads were 32 rows x 4KB
//      stride x 64B fragments per inst (~64 transactions). New mapping:
//      inst j, lane L -> row wave*32+j*8+(L>>3), k (L&7)*4..+3: 8x128B
//      contiguous segments/inst. Write side re-derived (p_j=wave*16+j*4+x,
//      slot=((b^(j&1))<<2)|(h^x)); read side IDENTICAL to R20 (which passed
//      -> layout + vmcnt counts validated). WRITEA moved pre-barrier (off the
//      barrier->MFMA critical path; target buf free since iter s-1's close).
//      k_wt/attn/oproj unchanged (R16/R17-proven).

typedef unsigned short u16;
typedef unsigned int u32;
using short8  = __attribute__((ext_vector_type(8))) short;   // 8 x bf16 (4 VGPRs)
using floatx4 = __attribute__((ext_vector_type(4))) float;

__device__ inline u16 f2bf(float x) {
  union { float f; u32 u; } v; v.f = x;
  u32 r = (v.u + 0x7fffu + ((v.u >> 16) & 1u)) >> 16;  // RNE
  return (u16)r;
}

__device__ inline u32 cvtpk(float a, float b) {   // 2 f32 -> packed 2 bf16 (RNE)
  u32 r;
  asm("v_cvt_pk_bf16_f32 %0, %1, %2" : "=v"(r) : "v"(a), "v"(b));
  return r;
}

__device__ inline float fast_exp2(float x) {
#if __has_builtin(__builtin_amdgcn_exp2f)
  return __builtin_amdgcn_exp2f(x);   // v_exp_f32 (natively exp2)
#else
  return exp2f(x);
#endif
}

#define MFMA(a, b, c) __builtin_amdgcn_mfma_f32_16x16x32_bf16(a, b, c, 0, 0, 0)

__device__ inline void async_lds16(const void* g, void* l) {
  __builtin_amdgcn_global_load_lds(
      (const __attribute__((address_space(1))) void*)g,
      (__attribute__((address_space(3))) void*)l, 16, 0, 0);
}

// Counted waits + raw barrier (T4). sched_barrier(0) pins ordering (rule #18).
#define WAIT_VM(n) { asm volatile("s_waitcnt vmcnt(" #n ")" ::: "memory"); \
                     __builtin_amdgcn_sched_barrier(0); }
#define WAIT_LGKM0 { asm volatile("s_waitcnt lgkmcnt(0)" ::: "memory"); \
                     __builtin_amdgcn_sched_barrier(0); }
#define SBAR       { __builtin_amdgcn_s_barrier(); \
                     __builtin_amdgcn_sched_barrier(0); }

// ------------- W [K][N] fp32 -> Wt [N][K] bf16, one 64x64 tile per block -------
__device__ __forceinline__
void transpose_body(int bid, const float* __restrict__ Wq, const float* __restrict__ Wk,
                    const float* __restrict__ Wv, const float* __restrict__ Wo,
                    u16* __restrict__ WqT, u16* __restrict__ WkvT, u16* __restrict__ WoT,
                    float* __restrict__ tile /* [64][68] floats */) {
  const int z = bid >> 8;
  const float* W; u16* Wt; int K;
  if      (z == 0) { W = Wq; Wt = WqT;               K = 1024; }
  else if (z == 1) { W = Wk; Wt = WkvT;              K = 768;  }
  else if (z == 2) { W = Wv; Wt = WkvT + 1024 * 768; K = 768;  }
  else             { W = Wo; Wt = WoT;               K = 1024; }
  const int k0 = ((bid >> 4) & 15) * 64, n0 = (bid & 15) * 64;
  if (k0 >= K) return;  // block-uniform guard
  const int N = 1024;
  const int t = threadIdx.x;
  for (int p = 0; p < 4; ++p) {
    int cid = p * 256 + t;
    int row = cid >> 4, c = cid & 15;
    float4 v = *(const float4*)&W[(long)(k0 + row) * N + n0 + c * 4];
    tile[row * 68 + c * 4 + 0] = v.x; tile[row * 68 + c * 4 + 1] = v.y;
    tile[row * 68 + c * 4 + 2] = v.z; tile[row * 68 + c * 4 + 3] = v.w;
  }
  __syncthreads();
  for (int p = 0; p < 2; ++p) {
    int oc = p * 256 + t;
    int n = oc >> 3, c = oc & 7;
    u16 tmp[8];
    for (int s = 0; s < 8; ++s) tmp[s] = f2bf(tile[(c * 8 + s) * 68 + n]);
    *(short8*)&Wt[(long)(n0 + n) * K + k0 + c * 8] = *(short8*)tmp;
  }
}

// ---------- weight-transpose kernel: Wq, Wk, Wv (768 blocks) ----------
__global__ __launch_bounds__(256)
void k_wt(const float* __restrict__ Wq, const float* __restrict__ Wk,
          const float* __restrict__ Wv,
          u16* __restrict__ WqT, u16* __restrict__ WkvT) {
  __shared__ __align__(16) float tile[64 * 68];
  transpose_body(blockIdx.x, Wq, Wk, Wv, nullptr, WqT, WkvT, nullptr, tile);
}

// ------- fp32-A GEMM body: BK=32 dbuf, coalesced reg-staged A (inline cast),
// gload_lds B, counted vmcnt. LDS per buffer: {A 4096 | B 4096} u16 (16 KB);
// 2 buffers. Epilogue staging reuses smem (needs 17664 u16 total).
__device__ __forceinline__
void gemm_f32a_body(const float* __restrict__ Af, const u16* __restrict__ Bt,
                    u16* __restrict__ Cb, u16* __restrict__ vt_out,
                    int K, int ldc, int lin, int mt_per_xcd, u16* smem) {
  const int tid  = threadIdx.x;
  const int wave = tid >> 6, lane = tid & 63;
  const int l15  = lane & 15, quad = lane >> 4;
  const int wm   = (wave >> 1) * 64, wn = (wave & 1) * 64;
  const int xcd  = lin & 7, slot = lin >> 3;
  const int mt   = xcd * mt_per_xcd + (slot % mt_per_xcd);
  const int nti  = slot / mt_per_xcd;
  const long m0  = (long)mt * 128, n0 = (long)nti * 128;

  // B via gload_lds + SOURCE swizzle (rule #21), T2 pair-row layout (verified)
  const int pl  = lane >> 3;
  const int gg  = (lane & 7) ^ pl;
  const int ro  = pl * 2 + (gg >> 2);
  const int co  = (gg & 3) * 8;
  const u16* Bw = Bt + (n0 + wave * 32 + ro) * (long)K + co;

  // A reg-staged from fp32, COALESCED: inst j (0..3), lane L reads row
  // wave*32 + j*8 + (L>>3), k = (L&7)*4..+3 (float4). 8 lanes cover one
  // row's 32 k -> per inst 8 x 128B contiguous segments.
  const int lr  = lane >> 3;            // 0..7
  const int lk  = lane & 7;             // 0..7
  const float* Awf = Af + (m0 + wave * 32 + lr) * (long)K + lk * 4;
  // write-side (re-derived, matches R20-validated read layout):
  //   p_j = wave*16 + j*4 + x;  slot_j = ((b^(j&1))<<2) | (h^x)
  //   with x=lr>>1, b=lr&1, h=lk>>1, w=lk&1; off2/3 = off0/1 + 512.
  const int xb  = lr >> 1, bb_ = lr & 1, hh = lk >> 1, wlo = lk & 1;
  const int off0 = (wave * 16 + xb) * 64 + (((bb_ << 2) | (hh ^ xb)) * 8) + wlo * 4;
  const int off1 = (wave * 16 + 4 + xb) * 64 + ((((bb_ ^ 1) << 2) | (hh ^ xb)) * 8) + wlo * 4;

  const int rdo  = ((((l15 & 1) << 2) | quad) ^ (l15 >> 1)) * 8;
  const int aoff = wm * 32 + (l15 >> 1) * 64 + rdo;
  const int boff = wn * 32 + (l15 >> 1) * 64 + rdo;

  u16* const buf0 = smem;          // {A 4096 | B 4096} u16
  u16* const buf1 = smem + 8192;

#define LOADA(a0, a1, a2, a3, kk) {                                           \
    a0 = *(const float4*)(Awf + (kk));                                        \
    a1 = *(const float4*)(Awf + (long)8  * K + (kk));                         \
    a2 = *(const float4*)(Awf + (long)16 * K + (kk));                         \
    a3 = *(const float4*)(Awf + (long)24 * K + (kk)); }
#define STAGEB(bb, kk) {                                                      \
    async_lds16(Bw + (kk),                (bb) + 4096 + wave * 1024);         \
    async_lds16(Bw + 16 * (long)K + (kk), (bb) + 4096 + wave * 1024 + 512); }
#define WRITEA(bb, a0, a1, a2, a3) {                                          \
    u32 w0_[2] = {cvtpk(a0.x, a0.y), cvtpk(a0.z, a0.w)};                      \
    u32 w1_[2] = {cvtpk(a1.x, a1.y), cvtpk(a1.z, a1.w)};                      \
    u32 w2_[2] = {cvtpk(a2.x, a2.y), cvtpk(a2.z, a2.w)};                      \
    u32 w3_[2] = {cvtpk(a3.x, a3.y), cvtpk(a3.z, a3.w)};                      \
    *(uint2*)&(bb)[off0]       = *(uint2*)w0_;                                \
    *(uint2*)&(bb)[off1]       = *(uint2*)w1_;                                \
    *(uint2*)&(bb)[off0 + 512] = *(uint2*)w2_;                                \
    *(uint2*)&(bb)[off1 + 512] = *(uint2*)w3_; }
#define COMPUTE(bb) { short8 af[4], bfr[4];                                    \
    for (int i = 0; i < 4; ++i) af[i]  = *(const short8*)&(bb)[aoff + i * 512];\
    for (int j = 0; j < 4; ++j)                                                \
      bfr[j] = *(const short8*)&(bb)[4096 + boff + j * 512];                   \
    for (int i = 0; i < 4; ++i)                                                \
      for (int j = 0; j < 4; ++j)                                              \
        acc[i][j] = MFMA(af[i], bfr[j], acc[i][j]); }

  floatx4 acc[4][4] = {};
  float4 rA0, rA1, rA2, rA3, rB0, rB1, rB2, rB3;
  const int NS = K >> 5;                 // 32 (K=1024) or 24 (K=768): even

  // Prologue: A(0)->rA*, B(0)->buf0, A(1)->rB*; write A(0).
  LOADA(rA0, rA1, rA2, rA3, 0);
  STAGEB(buf0, 0);
  LOADA(rB0, rB1, rB2, rB3, 32);
  WAIT_VM(6);                            // A(0) ready; B(0)(2)+A(1)(4) fly
  WRITEA(buf0, rA0, rA1, rA2, rA3);
  WAIT_LGKM0;

  // iter s: stage B(s+1); load A(s+2); wait; WRITEA A(s+1) into next buf
  // (pre-barrier: bn free since iter s-1's close); barrier; compute cur buf.
#define ITER(s, bc, bn, c0, c1, c2, c3, n0_, n1_, n2_, n3_) {                  \
    if ((s) + 1 < NS) STAGEB(bn, ((s) + 1) * 32);                              \
    if ((s) + 2 < NS) LOADA(n0_, n1_, n2_, n3_, ((s) + 2) * 32);               \
    if ((s) + 2 < NS)      { WAIT_VM(6); }                                     \
    else if ((s) + 1 < NS) { WAIT_VM(2); }                                     \
    else                   { WAIT_VM(0); }                                     \
    if ((s) + 1 < NS) WRITEA(bn, c0, c1, c2, c3);                              \
    SBAR;                                                                      \
    COMPUTE(bc);                                                               \
    WAIT_LGKM0;                                                                \
    SBAR; }

  for (int sp = 0; sp < NS; sp += 2) {   // NS even -> static reg rotation
    ITER(sp,     buf0, buf1, rB0, rB1, rB2, rB3, rA0, rA1, rA2, rA3);
    ITER(sp + 1, buf1, buf0, rA0, rA1, rA2, rA3, rB0, rB1, rB2, rB3);
  }
#undef ITER
#undef LOADA
#undef STAGEB
#undef WRITEA
#undef COMPUTE

  // epilogue: bf16 C via LDS staging (+ optional vT transpose) -- unchanged
  for (int i = 0; i < 4; ++i)
    for (int j = 0; j < 4; ++j)
      for (int r = 0; r < 4; ++r)
        smem[(wm + i * 16 + quad * 4 + r) * 138 + wn + j * 16 + l15] = f2bf(acc[i][j][r]);
  __syncthreads();
  if (vt_out && nti >= 8) {
    const int h  = nti - 8;
    const int bq = (int)(m0 >> 9);
    const int l0 = (int)(m0 & 511);
    u16* vbase = vt_out + ((long)(bq * 8 + h) * 128) * 512;
    for (int pp = 0; pp < 8; ++pp) {
      int cid = pp * 256 + tid;
      int d = cid >> 4, c = cid & 15;
      u16 tmp[8];
      for (int s = 0; s < 8; ++s) tmp[s] = smem[(c * 8 + s) * 138 + d];
      *(short8*)&vbase[(long)d * 512 + l0 + c * 8] = *(short8*)tmp;
    }
  } else {
    for (int pp = 0; pp < 8; ++pp) {
      int cid = pp * 256 + tid;
      int row = cid >> 4, c = cid & 15;
      short8 v = *(const short8*)&smem[row * 138 + c * 8];
      *(short8*)&Cb[(m0 + row) * (long)ldc + n0 + c * 8] = v;
    }
  }
}

// ------- bf16 GEMM body (oproj): BK=32 TRIPLE buffer, R17-proven -------
// smem >= 24576 u16 (48 KB): buf k at smem + k*8192 (A 4096 | B 4096).
__device__ __forceinline__
void gemm_body(const u16* __restrict__ A, const u16* __restrict__ Bt,
               float* __restrict__ Cf, const float* __restrict__ bias,
               int K, int ldc, int lin, int mt_per_xcd, u16* smem) {
  const int tid  = threadIdx.x;
  const int wave = tid >> 6, lane = tid & 63;
  const int l15  = lane & 15, quad = lane >> 4;
  const int wm   = (wave >> 1) * 64, wn = (wave & 1) * 64;
  const int xcd  = lin & 7, slot = lin >> 3;
  const int mt   = xcd * mt_per_xcd + (slot % mt_per_xcd);
  const int nti  = slot / mt_per_xcd;
  const long m0  = (long)mt * 128, n0 = (long)nti * 128;

  const int pl  = lane >> 3;
  const int gg  = (lane & 7) ^ pl;
  const int ro  = pl * 2 + (gg >> 2);
  const int co  = (gg & 3) * 8;
  const u16* Aw = A  + (m0 + wave * 32 + ro) * (long)K + co;
  const u16* Bw = Bt + (n0 + wave * 32 + ro) * (long)K + co;
  const int rdo  = ((((l15 & 1) << 2) | quad) ^ (l15 >> 1)) * 8;
  const int aoff = wm * 32 + (l15 >> 1) * 64 + rdo;
  const int boff = wn * 32 + (l15 >> 1) * 64 + rdo;

#define STAGE_G(Bse, kk)                                                   \
  { u16* Ab_ = (Bse); u16* Bb_ = (Bse) + 4096;                             \
    async_lds16(Aw + (kk),                Ab_ + wave * 1024);              \
    async_lds16(Aw + 16 * (long)K + (kk), Ab_ + wave * 1024 + 512);        \
    async_lds16(Bw + (kk),                Bb_ + wave * 1024);              \
    async_lds16(Bw + 16 * (long)K + (kk), Bb_ + wave * 1024 + 512); }

  floatx4 acc[4][4] = {};
  const int NS = K >> 5;
  STAGE_G(smem, 0);
  STAGE_G(smem + 8192, 32);
  int cb = 0, nb = 2;
  for (int s = 0; s < NS; ++s) {
    u16* Ac = smem + cb * 8192; u16* Bc = Ac + 4096;
    if (s + 2 < NS) {
      STAGE_G(smem + nb * 8192, (s + 2) * 32);
      WAIT_VM(8);
    } else if (s + 1 < NS) {
      WAIT_VM(4);
    } else {
      WAIT_VM(0);
    }
    SBAR;
    short8 af[4], bfr[4];
    for (int i = 0; i < 4; ++i) af[i]  = *(const short8*)&Ac[aoff + i * 512];
    for (int j = 0; j < 4; ++j) bfr[j] = *(const short8*)&Bc[boff + j * 512];
    for (int i = 0; i < 4; ++i)
      for (int j = 0; j < 4; ++j)
        acc[i][j] = MFMA(af[i], bfr[j], acc[i][j]);
    WAIT_LGKM0;
    SBAR;
    cb = (cb == 2) ? 0 : cb + 1;
    nb = (nb == 2) ? 0 : nb + 1;
  }
#undef STAGE_G

  for (int i = 0; i < 4; ++i)
    for (int j = 0; j < 4; ++j) {
      long row = m0 + wm + i * 16 + quad * 4;
      long col = n0 + wn + j * 16 + l15;
      float b = bias ? bias[col] : 0.f;
      for (int r = 0; r < 4; ++r) Cf[(row + r) * (long)ldc + col] = acc[i][j][r] + b;
    }
}

// ---- fused Q+KV projection + Wo transpose: 1024 blocks ----
// 0..511: Q-proj (fp32 A). 512..767: KV-proj (fp32 A). 768..1023: Wo transpose.
__global__ __launch_bounds__(256)
void k_proj_qkv(const float* __restrict__ q, const float* __restrict__ kv,
                const u16* __restrict__ WqT, const u16* __restrict__ WkvT,
                const float* __restrict__ Wo, u16* __restrict__ WoT,
                u16* __restrict__ qp, u16* __restrict__ kp, u16* __restrict__ vT) {
  __shared__ __align__(16) u16 smem[17664];   // loop 32KB; epilogue 34.5KB
  const int bid = blockIdx.x;
  if (bid < 512)
    gemm_f32a_body(q, WqT, qp, nullptr, 1024, 1024, bid, 8, smem);
  else if (bid < 768)
    gemm_f32a_body(kv, WkvT, kp, vT, 768, 1024, bid - 512, 2, smem);
  else
    transpose_body(bid, nullptr, nullptr, nullptr, Wo,
                   nullptr, nullptr, WoT, (float*)smem);
}

// ------- flash attention: 8 waves x qtile=128, counted-vmcnt K/V staging -------
// 512 blocks x 512 threads. LDS: Ks 16KB + Vs 16KB + P 8x2KB = 48KB.
__global__ __launch_bounds__(512)
void k_attn(const u16* __restrict__ qp, const u16* __restrict__ kp,
            const u16* __restrict__ vT, u16* __restrict__ ctx) {
  __shared__ __align__(16) u16 smem[24576];   // 49152 B
  u16* Ks = smem;            // [64 k][128 d], granule g at g^(k&15)
  u16* Vs = smem + 8192;     // [128 d][64 k], granule g at g^(d&7)
  const int lin  = blockIdx.x;                 // 0..511
  const int tid  = threadIdx.x;
  const int wave = tid >> 6, lane = tid & 63;  // wave 0..7
  u16* Pw = smem + 16384 + wave * 1024;        // per-wave P [16 r][64 k], g^(row&7)
  const int l15  = lane & 15, quad = lane >> 4;
  const int xcd  = lin & 7, slot = lin >> 3;   // slot 0..63
  const int pairIdx = xcd * 4 + (slot & 3);    // 0..31 (b,h)
  const int b = pairIdx >> 3, h = pairIdx & 7;
  const int qtile = slot >> 2;                 // 0..15
  const long rowbase = (long)b * 2048 + qtile * 128 + wave * 16;
  const float sc = 0.08838834764831845f * 1.4426950408889634f;  // scale*log2(e)

  short8 aQ[4];
  for (int dc = 0; dc < 4; ++dc)
    aQ[dc] = *(const short8*)&qp[(rowbase + l15) * 1024 + h * 128 + dc * 32 + quad * 8];

  floatx4 O[8] = {};
  float lsum[4] = {};
  const u16* kpb   = kp + ((long)b * 512) * 1024 + h * 128;
  const u16* vbase = vT + ((long)(b * 8 + h) * 128) * 512;

  const int krow = lane >> 4;
  const int kpos = lane & 15;
  const int vrow = lane >> 3;
  const int vpos = lane & 7;

#define STAGE_K(t)                                                             \
  for (int i = 0; i < 2; ++i) {                                                \
    int inst = wave * 2 + i;                                                   \
    int row  = inst * 4 + krow;                                                \
    int g    = kpos ^ (row & 15);                                              \
    async_lds16(kpb + (long)((t) * 64 + row) * 1024 + g * 8, &Ks[inst * 512]); \
  }
#define STAGE_V(t)                                                             \
  for (int i = 0; i < 2; ++i) {                                                \
    int inst = wave * 2 + i;                                                   \
    int d    = inst * 8 + vrow;                                                \
    int g    = vpos ^ (d & 7);                                                 \
    async_lds16(vbase + (long)d * 512 + (t) * 64 + g * 8, &Vs[inst * 512]);    \
  }

  STAGE_K(0);
  STAGE_V(0);
  for (int t = 0; t < 8; ++t) {
    WAIT_VM(2);                 // K(t) landed (V(t) may still fly)
    SBAR;
    floatx4 S[4] = {};
    __builtin_amdgcn_s_setprio(1);
    for (int dc = 0; dc < 4; ++dc)
      for (int ks = 0; ks < 4; ++ks) {
        int k = ks * 16 + l15;
        short8 bk = *(const short8*)&Ks[k * 128 + (((dc * 4 + quad) ^ l15) * 8)];
        S[ks] = MFMA(aQ[dc], bk, S[ks]);
      }
    __builtin_amdgcn_s_setprio(0);
    WAIT_LGKM0;                 // Ks reads retired
    SBAR;                       // all waves done with Ks
    if (t < 7) STAGE_K(t + 1);  // flies over softmax + PV
    for (int ks = 0; ks < 4; ++ks)
      for (int r = 0; r < 4; ++r) {
        float p = fast_exp2(S[ks][r] * sc);
        lsum[r] += p;
        int row = quad * 4 + r;
        int g   = (ks * 2 + (l15 >> 3)) ^ (row & 7);
        Pw[row * 64 + g * 8 + (l15 & 7)] = f2bf(p);
      }
    short8 aP[2];
    for (int kc = 0; kc < 2; ++kc)
      aP[kc] = *(const short8*)&Pw[l15 * 64 + (((kc * 4 + quad) ^ (l15 & 7)) * 8)];
    if (t < 7) { WAIT_VM(2); }  // V(t) landed (K(t+1) may still fly)
    else       { WAIT_VM(0); }
    SBAR;
    __builtin_amdgcn_s_setprio(1);
    for (int j = 0; j < 8; ++j) {
      int d = j * 16 + l15;
      short8 bV0 = *(const short8*)&Vs[d * 64 + ((quad ^ (l15 & 7)) * 8)];
      short8 bV1 = *(const short8*)&Vs[d * 64 + (((4 + quad) ^ (l15 & 7)) * 8)];
      O[j] = MFMA(aP[0], bV0, O[j]);
      O[j] = MFMA(aP[1], bV1, O[j]);
    }
    __builtin_amdgcn_s_setprio(0);
    WAIT_LGKM0;                 // Vs reads retired
    SBAR;                       // all waves done with Vs
    if (t < 7) STAGE_V(t + 1);  // flies over QK(t+1) + softmax
  }
#undef STAGE_K
#undef STAGE_V

  for (int r = 0; r < 4; ++r) {
    float sum = lsum[r];
    for (int off = 1; off < 16; off <<= 1) sum += __shfl_xor(sum, off);
    lsum[r] = 1.f / sum;
  }
  for (int j = 0; j < 8; ++j)
    for (int r = 0; r < 4; ++r)
      ctx[(rowbase + quad * 4 + r) * 1024 + h * 128 + j * 16 + l15] =
          f2bf(O[j][r] * lsum[r]);
}

// ---------------- O-projection (R17 triple-buffer body) ----------------
__global__ __launch_bounds__(256)
void k_oproj(const u16* __restrict__ ctx, const u16* __restrict__ WoT,
             float* __restrict__ out, const float* __restrict__ bo) {
  __shared__ __align__(16) u16 smem[24576];   // 48 KB: 3 x BK=32 buffers
  gemm_body(ctx, WoT, out, bo, 1024, 1024, blockIdx.x, 8, smem);
}

extern "C" void kernel_launch(void* const* d_in, const int* in_sizes, int n_in,
                              void* d_out, int out_size, void* d_ws, size_t ws_size,
                              hipStream_t stream) {
  const float* q  = (const float*)d_in[0];
  const float* kv = (const float*)d_in[1];
  const float* Wq = (const float*)d_in[2];
  const float* Wk = (const float*)d_in[3];
  const float* Wv = (const float*)d_in[4];
  const float* Wo = (const float*)d_in[5];
  const float* bo = (const float*)d_in[6];
  float* out = (float*)d_out;

  char* ws = (char*)d_ws;
  u16* WqT   = (u16*)(ws + 19922944);       //  2 MB   [1024][1024]
  u16* WkvT  = (u16*)(ws + 22020096);       //  3 MB   [2048][768]
  u16* WoT   = (u16*)(ws + 25165824);       //  2 MB   [1024][1024]
  u16* qp    = (u16*)(ws + 27262976);       // 16 MB   [8192][1024]
  u16* kp    = (u16*)(ws + 44040192);       //  4 MB   [2048][1024]
  u16* vT    = (u16*)(ws + 52428800);       //  4 MB   [B][H][128][512]
  u16* ctx   = (u16*)(ws + 56623104);       // 16 MB   [8192][1024]

  k_wt<<<768, 256, 0, stream>>>(Wq, Wk, Wv, WqT, WkvT);
  k_proj_qkv<<<1024, 256, 0, stream>>>(q, kv, WqT, WkvT, Wo, WoT, qp, kp, vT);
  k_attn<<<512, 512, 0, stream>>>(qp, kp, vT, ctx);
  k_oproj<<<512, 256, 0, stream>>>(ctx, WoT, out, bo);
}

// Round 11
// 182.615 us; speedup vs baseline: 1.0694x; 1.0694x over previous
//
#include <hip/hip_runtime.h>

// CrossAttention on MI355X (gfx950), bf16 MFMA path.
// B=4, Lq=2048, Lkv=512, dim_q=1024, dim_kv=768, H=8, hd=128.
// R22: revert to R17 config (best measured, 181.7us) after R19-R21 closed the
//      f32a inline-cast axis (58-60us proj vs ~45us cast+bf16-proj; FETCH
//      unchanged under coalescing -> L2 absorbs, cost is the reg-chain in the
//      critical path). One proven tweak kept from R20/R21: Wo transpose rides
//      in the proj dispatch (bid 768..1023, proven correct there); prep is
//      cast + Wq/Wk/Wv transposes only (5632 blocks).
//      Phases: k_prep -> k_proj_qkv(1024) -> k_attn(512x512) -> k_oproj.
//      GEMM: BK=32 triple-buffer counted-vmcnt (R17). attn: 8-wave qtile=128.

typedef unsigned short u16;
typedef unsigned int u32;
using short8  = __attribute__((ext_vector_type(8))) short;   // 8 x bf16 (4 VGPRs)
using floatx4 = __attribute__((ext_vector_type(4))) float;

__device__ inline u16 f2bf(float x) {
  union { float f; u32 u; } v; v.f = x;
  u32 r = (v.u + 0x7fffu + ((v.u >> 16) & 1u)) >> 16;  // RNE
  return (u16)r;
}

__device__ inline float fast_exp2(float x) {
#if __has_builtin(__builtin_amdgcn_exp2f)
  return __builtin_amdgcn_exp2f(x);   // v_exp_f32 (natively exp2)
#else
  return exp2f(x);
#endif
}

#define MFMA(a, b, c) __builtin_amdgcn_mfma_f32_16x16x32_bf16(a, b, c, 0, 0, 0)

__device__ inline void async_lds16(const void* g, void* l) {
  __builtin_amdgcn_global_load_lds(
      (const __attribute__((address_space(1))) void*)g,
      (__attribute__((address_space(3))) void*)l, 16, 0, 0);
}

// Counted waits + raw barrier (T4). sched_barrier(0) pins ordering (rule #18).
#define WAIT_VM(n) { asm volatile("s_waitcnt vmcnt(" #n ")" ::: "memory"); \
                     __builtin_amdgcn_sched_barrier(0); }
#define WAIT_LGKM0 { asm volatile("s_waitcnt lgkmcnt(0)" ::: "memory"); \
                     __builtin_amdgcn_sched_barrier(0); }
#define SBAR       { __builtin_amdgcn_s_barrier(); \
                     __builtin_amdgcn_sched_barrier(0); }

// ------------- W [K][N] fp32 -> Wt [N][K] bf16, one 64x64 tile per block -------
__device__ __forceinline__
void transpose_body(int bid, const float* __restrict__ Wq, const float* __restrict__ Wk,
                    const float* __restrict__ Wv, const float* __restrict__ Wo,
                    u16* __restrict__ WqT, u16* __restrict__ WkvT, u16* __restrict__ WoT,
                    float* __restrict__ tile /* [64][68] floats */) {
  const int z = bid >> 8;
  const float* W; u16* Wt; int K;
  if      (z == 0) { W = Wq; Wt = WqT;               K = 1024; }
  else if (z == 1) { W = Wk; Wt = WkvT;              K = 768;  }
  else if (z == 2) { W = Wv; Wt = WkvT + 1024 * 768; K = 768;  }
  else             { W = Wo; Wt = WoT;               K = 1024; }
  const int k0 = ((bid >> 4) & 15) * 64, n0 = (bid & 15) * 64;
  if (k0 >= K) return;  // block-uniform guard
  const int N = 1024;
  const int t = threadIdx.x;
  for (int p = 0; p < 4; ++p) {
    int cid = p * 256 + t;
    int row = cid >> 4, c = cid & 15;
    float4 v = *(const float4*)&W[(long)(k0 + row) * N + n0 + c * 4];
    tile[row * 68 + c * 4 + 0] = v.x; tile[row * 68 + c * 4 + 1] = v.y;
    tile[row * 68 + c * 4 + 2] = v.z; tile[row * 68 + c * 4 + 3] = v.w;
  }
  __syncthreads();
  for (int p = 0; p < 2; ++p) {
    int oc = p * 256 + t;
    int n = oc >> 3, c = oc & 7;
    u16 tmp[8];
    for (int s = 0; s < 8; ++s) tmp[s] = f2bf(tile[(c * 8 + s) * 68 + n]);
    *(short8*)&Wt[(long)(n0 + n) * K + k0 + c * 8] = *(short8*)tmp;
  }
}

// ---------- prep kernel: fp32->bf16 casts (bid<4864) + Wq/Wk/Wv transposes ----
__global__ __launch_bounds__(256)
void k_prep(const float* __restrict__ q, const float* __restrict__ kv,
            u16* __restrict__ q_bf, u16* __restrict__ kv_bf,
            const float* __restrict__ Wq, const float* __restrict__ Wk,
            const float* __restrict__ Wv,
            u16* __restrict__ WqT, u16* __restrict__ WkvT) {
  __shared__ __align__(16) float tile[64 * 68];
  const int bid = blockIdx.x;
  if (bid < 4864) {
    int i = bid * 256 + threadIdx.x;   // 4864*256 == 1245184 exactly
    const float* src; u16* dst; int idx;
    if (i < 1048576) { src = q;  dst = q_bf;  idx = i; }
    else             { src = kv; dst = kv_bf; idx = i - 1048576; }
    float4 a = ((const float4*)src)[2 * idx];
    float4 b = ((const float4*)src)[2 * idx + 1];
    u16 t[8] = {f2bf(a.x), f2bf(a.y), f2bf(a.z), f2bf(a.w),
                f2bf(b.x), f2bf(b.y), f2bf(b.z), f2bf(b.w)};
    ((short8*)dst)[idx] = *(short8*)t;
  } else {
    // bid' 0..767 -> z 0..2 (Wq, Wk, Wv)
    transpose_body(bid - 4864, Wq, Wk, Wv, nullptr, WqT, WkvT, nullptr, tile);
  }
}

// ------- bf16 GEMM body: BK=32 TRIPLE buffer, 3-deep counted-vmcnt pipeline -------
// smem must be >= 24576 u16 (48 KB): buf k at smem + k*8192 (A 4096 | B 4096).
__device__ __forceinline__
void gemm_body(const u16* __restrict__ A, const u16* __restrict__ Bt,
               u16* __restrict__ Cb, float* __restrict__ Cf,
               const float* __restrict__ bias, u16* __restrict__ vt_out,
               int K, int ldc, int lin, int mt_per_xcd, u16* smem) {
  const int tid  = threadIdx.x;
  const int wave = tid >> 6, lane = tid & 63;
  const int l15  = lane & 15, quad = lane >> 4;
  const int wm   = (wave >> 1) * 64, wn = (wave & 1) * 64;
  const int xcd  = lin & 7, slot = lin >> 3;
  const int mt   = xcd * mt_per_xcd + (slot % mt_per_xcd);
  const int nti  = slot / mt_per_xcd;
  const long m0  = (long)mt * 128, n0 = (long)nti * 128;

  // T2 pair-row layout: LDS buf = [64 pair-rows][64 u16]; pair-row p packs
  // rows {2p,2p+1} x 32 k. Granule g=(r&1)*4+k/8 stored at g^(p&7); involution
  // applied at the SOURCE addr (rule #21), LDS dest linear.
  const int pl  = lane >> 3;
  const int gg  = (lane & 7) ^ pl;
  const int ro  = pl * 2 + (gg >> 2);
  const int co  = (gg & 3) * 8;
  const u16* Aw = A  + (m0 + wave * 32 + ro) * (long)K + co;
  const u16* Bw = Bt + (n0 + wave * 32 + ro) * (long)K + co;
  const int rdo  = ((((l15 & 1) << 2) | quad) ^ (l15 >> 1)) * 8;
  const int aoff = wm * 32 + (l15 >> 1) * 64 + rdo;
  const int boff = wn * 32 + (l15 >> 1) * 64 + rdo;

  // stage into buffer base Bse (u16*): A at Bse, B at Bse+4096
#define STAGE_G(Bse, kk)                                                   \
  { u16* Ab_ = (Bse); u16* Bb_ = (Bse) + 4096;                             \
    async_lds16(Aw + (kk),                Ab_ + wave * 1024);              \
    async_lds16(Aw + 16 * (long)K + (kk), Ab_ + wave * 1024 + 512);        \
    async_lds16(Bw + (kk),                Bb_ + wave * 1024);              \
    async_lds16(Bw + 16 * (long)K + (kk), Bb_ + wave * 1024 + 512); }

  floatx4 acc[4][4] = {};
  const int NS = K >> 5;                 // 32 (K=1024) or 24 (K=768)
  STAGE_G(smem, 0);                      // stage 0 -> buf 0
  STAGE_G(smem + 8192, 32);              // stage 1 -> buf 1
  int cb = 0, nb = 2;                    // compute buf, next-stage buf
  for (int s = 0; s < NS; ++s) {
    u16* Ac = smem + cb * 8192; u16* Bc = Ac + 4096;
    if (s + 2 < NS) {                    // issue stage s+2 (buf nb free)
      STAGE_G(smem + nb * 8192, (s + 2) * 32);
      WAIT_VM(8);                        // stage(s) landed; s+1, s+2 in flight
    } else if (s + 1 < NS) {
      WAIT_VM(4);
    } else {
      WAIT_VM(0);
    }
    SBAR;                                // all waves' stage(s) landed
    short8 af[4], bfr[4];
    for (int i = 0; i < 4; ++i) af[i]  = *(const short8*)&Ac[aoff + i * 512];
    for (int j = 0; j < 4; ++j) bfr[j] = *(const short8*)&Bc[boff + j * 512];
    for (int i = 0; i < 4; ++i)
      for (int j = 0; j < 4; ++j)
        acc[i][j] = MFMA(af[i], bfr[j], acc[i][j]);
    WAIT_LGKM0;                          // this wave's reads of buf cb retired
    SBAR;                                // everyone done with buf cb
    cb = (cb == 2) ? 0 : cb + 1;
    nb = (nb == 2) ? 0 : nb + 1;
  }
#undef STAGE_G

  if (Cf) {
    for (int i = 0; i < 4; ++i)
      for (int j = 0; j < 4; ++j) {
        long row = m0 + wm + i * 16 + quad * 4;
        long col = n0 + wn + j * 16 + l15;
        float b = bias ? bias[col] : 0.f;
        for (int r = 0; r < 4; ++r) Cf[(row + r) * (long)ldc + col] = acc[i][j][r] + b;
      }
    return;
  }
  for (int i = 0; i < 4; ++i)
    for (int j = 0; j < 4; ++j)
      for (int r = 0; r < 4; ++r)
        smem[(wm + i * 16 + quad * 4 + r) * 138 + wn + j * 16 + l15] = f2bf(acc[i][j][r]);
  __syncthreads();
  if (vt_out && nti >= 8) {
    const int h  = nti - 8;
    const int bq = (int)(m0 >> 9);
    const int l0 = (int)(m0 & 511);
    u16* vbase = vt_out + ((long)(bq * 8 + h) * 128) * 512;
    for (int p = 0; p < 8; ++p) {
      int cid = p * 256 + tid;
      int d = cid >> 4, c = cid & 15;
      u16 tmp[8];
      for (int s = 0; s < 8; ++s) tmp[s] = smem[(c * 8 + s) * 138 + d];
      *(short8*)&vbase[(long)d * 512 + l0 + c * 8] = *(short8*)tmp;
    }
  } else {
    for (int p = 0; p < 8; ++p) {
      int cid = p * 256 + tid;
      int row = cid >> 4, c = cid & 15;
      short8 v = *(const short8*)&smem[row * 138 + c * 8];
      *(short8*)&Cb[(m0 + row) * (long)ldc + n0 + c * 8] = v;
    }
  }
}

// ---- fused Q+KV projection + Wo transpose: 1024 blocks ----
// 0..511: Q-proj. 512..767: KV-proj. 768..1023: Wo transpose (z=3 path).
__global__ __launch_bounds__(256)
void k_proj_qkv(const u16* __restrict__ q_bf, const u16* __restrict__ WqT,
                const u16* __restrict__ kv_bf, const u16* __restrict__ WkvT,
                const float* __restrict__ Wo, u16* __restrict__ WoT,
                u16* __restrict__ qp, u16* __restrict__ kp, u16* __restrict__ vT) {
  __shared__ __align__(16) u16 smem[24576];   // 48 KB: 3-buf (epilogue aliases)
  const int bid = blockIdx.x;
  if (bid < 512)
    gemm_body(q_bf, WqT, qp, nullptr, nullptr, nullptr, 1024, 1024, bid, 8, smem);
  else if (bid < 768)
    gemm_body(kv_bf, WkvT, kp, nullptr, nullptr, vT, 768, 1024, bid - 512, 2, smem);
  else  // bid 768..1023 -> bid>>8 == 3 -> Wo
    transpose_body(bid, nullptr, nullptr, nullptr, Wo,
                   nullptr, nullptr, WoT, (float*)smem);
}

// ------- flash attention: 8 waves x qtile=128, counted-vmcnt K/V staging -------
// 512 blocks x 512 threads. LDS: Ks 16KB + Vs 16KB + P 8x2KB = 48KB.
__global__ __launch_bounds__(512)
void k_attn(const u16* __restrict__ qp, const u16* __restrict__ kp,
            const u16* __restrict__ vT, u16* __restrict__ ctx) {
  __shared__ __align__(16) u16 smem[24576];   // 49152 B
  u16* Ks = smem;            // [64 k][128 d], granule g at g^(k&15)
  u16* Vs = smem + 8192;     // [128 d][64 k], granule g at g^(d&7)
  const int lin  = blockIdx.x;                 // 0..511
  const int tid  = threadIdx.x;
  const int wave = tid >> 6, lane = tid & 63;  // wave 0..7
  u16* Pw = smem + 16384 + wave * 1024;        // per-wave P [16 r][64 k], g^(row&7)
  const int l15  = lane & 15, quad = lane >> 4;
  const int xcd  = lin & 7, slot = lin >> 3;   // slot 0..63
  const int pairIdx = xcd * 4 + (slot & 3);    // 0..31 (b,h)
  const int b = pairIdx >> 3, h = pairIdx & 7;
  const int qtile = slot >> 2;                 // 0..15
  const long rowbase = (long)b * 2048 + qtile * 128 + wave * 16;
  const float sc = 0.08838834764831845f * 1.4426950408889634f;  // scale*log2(e)

  short8 aQ[4];
  for (int dc = 0; dc < 4; ++dc)
    aQ[dc] = *(const short8*)&qp[(rowbase + l15) * 1024 + h * 128 + dc * 32 + quad * 8];

  floatx4 O[8] = {};
  float lsum[4] = {};
  const u16* kpb   = kp + ((long)b * 512) * 1024 + h * 128;
  const u16* vbase = vT + ((long)(b * 8 + h) * 128) * 512;

  const int krow = lane >> 4;
  const int kpos = lane & 15;
  const int vrow = lane >> 3;
  const int vpos = lane & 7;

#define STAGE_K(t)                                                             \
  for (int i = 0; i < 2; ++i) {                                                \
    int inst = wave * 2 + i;                                                   \
    int row  = inst * 4 + krow;                                                \
    int g    = kpos ^ (row & 15);                                              \
    async_lds16(kpb + (long)((t) * 64 + row) * 1024 + g * 8, &Ks[inst * 512]); \
  }
#define STAGE_V(t)                                                             \
  for (int i = 0; i < 2; ++i) {                                                \
    int inst = wave * 2 + i;                                                   \
    int d    = inst * 8 + vrow;                                                \
    int g    = vpos ^ (d & 7);                                                 \
    async_lds16(vbase + (long)d * 512 + (t) * 64 + g * 8, &Vs[inst * 512]);    \
  }

  STAGE_K(0);
  STAGE_V(0);
  for (int t = 0; t < 8; ++t) {
    WAIT_VM(2);                 // K(t) landed (V(t) may still fly)
    SBAR;
    floatx4 S[4] = {};
    __builtin_amdgcn_s_setprio(1);
    for (int dc = 0; dc < 4; ++dc)
      for (int ks = 0; ks < 4; ++ks) {
        int k = ks * 16 + l15;
        short8 bk = *(const short8*)&Ks[k * 128 + (((dc * 4 + quad) ^ l15) * 8)];
        S[ks] = MFMA(aQ[dc], bk, S[ks]);
      }
    __builtin_amdgcn_s_setprio(0);
    WAIT_LGKM0;                 // Ks reads retired
    SBAR;                       // all waves done with Ks
    if (t < 7) STAGE_K(t + 1);  // flies over softmax + PV
    for (int ks = 0; ks < 4; ++ks)
      for (int r = 0; r < 4; ++r) {
        float p = fast_exp2(S[ks][r] * sc);
        lsum[r] += p;
        int row = quad * 4 + r;
        int g   = (ks * 2 + (l15 >> 3)) ^ (row & 7);
        Pw[row * 64 + g * 8 + (l15 & 7)] = f2bf(p);
      }
    short8 aP[2];
    for (int kc = 0; kc < 2; ++kc)
      aP[kc] = *(const short8*)&Pw[l15 * 64 + (((kc * 4 + quad) ^ (l15 & 7)) * 8)];
    if (t < 7) { WAIT_VM(2); }  // V(t) landed (K(t+1) may still fly)
    else       { WAIT_VM(0); }
    SBAR;
    __builtin_amdgcn_s_setprio(1);
    for (int j = 0; j < 8; ++j) {
      int d = j * 16 + l15;
      short8 bV0 = *(const short8*)&Vs[d * 64 + ((quad ^ (l15 & 7)) * 8)];
      short8 bV1 = *(const short8*)&Vs[d * 64 + (((4 + quad) ^ (l15 & 7)) * 8)];
      O[j] = MFMA(aP[0], bV0, O[j]);
      O[j] = MFMA(aP[1], bV1, O[j]);
    }
    __builtin_amdgcn_s_setprio(0);
    WAIT_LGKM0;                 // Vs reads retired
    SBAR;                       // all waves done with Vs
    if (t < 7) STAGE_V(t + 1);  // flies over QK(t+1) + softmax
  }
#undef STAGE_K
#undef STAGE_V

  for (int r = 0; r < 4; ++r) {
    float sum = lsum[r];
    for (int off = 1; off < 16; off <<= 1) sum += __shfl_xor(sum, off);
    lsum[r] = 1.f / sum;
  }
  for (int j = 0; j < 8; ++j)
    for (int r = 0; r < 4; ++r)
      ctx[(rowbase + quad * 4 + r) * 1024 + h * 128 + j * 16 + l15] =
          f2bf(O[j][r] * lsum[r]);
}

// ---------------- O-projection (R17 triple-buffer body) ----------------
__global__ __launch_bounds__(256)
void k_oproj(const u16* __restrict__ ctx, const u16* __restrict__ WoT,
             float* __restrict__ out, const float* __restrict__ bo) {
  __shared__ __align__(16) u16 smem[24576];   // 48 KB: 3 x BK=32 buffers
  gemm_body(ctx, WoT, nullptr, out, bo, nullptr, 1024, 1024, blockIdx.x, 8, smem);
}

extern "C" void kernel_launch(void* const* d_in, const int* in_sizes, int n_in,
                              void* d_out, int out_size, void* d_ws, size_t ws_size,
                              hipStream_t stream) {
  const float* q  = (const float*)d_in[0];
  const float* kv = (const float*)d_in[1];
  const float* Wq = (const float*)d_in[2];
  const float* Wk = (const float*)d_in[3];
  const float* Wv = (const float*)d_in[4];
  const float* Wo = (const float*)d_in[5];
  const float* bo = (const float*)d_in[6];
  float* out = (float*)d_out;

  char* ws = (char*)d_ws;
  u16* q_bf  = (u16*)(ws + 0);              // 16 MB
  u16* kv_bf = (u16*)(ws + 16777216);       //  3 MB
  u16* WqT   = (u16*)(ws + 19922944);       //  2 MB   [1024][1024]
  u16* WkvT  = (u16*)(ws + 22020096);       //  3 MB   [2048][768]
  u16* WoT   = (u16*)(ws + 25165824);       //  2 MB   [1024][1024]
  u16* qp    = (u16*)(ws + 27262976);       // 16 MB   [8192][1024]
  u16* kp    = (u16*)(ws + 44040192);       //  4 MB   [2048][1024]
  u16* vT    = (u16*)(ws + 52428800);       //  4 MB   [B][H][128][512]
  u16* ctx   = (u16*)(ws + 56623104);       // 16 MB   [8192][1024]

  k_prep<<<5632, 256, 0, stream>>>(q, kv, q_bf, kv_bf, Wq, Wk, Wv, WqT, WkvT);
  k_proj_qkv<<<1024, 256, 0, stream>>>(q_bf, WqT, kv_bf, WkvT, Wo, WoT,
                                       qp, kp, vT);
  k_attn<<<512, 512, 0, stream>>>(qp, kp, vT, ctx);
  k_oproj<<<512, 256, 0, stream>>>(ctx, WoT, out, bo);
}